// Round 1
// baseline (78178.088 us; speedup 1.0000x reference)
//
#include <hip/hip_runtime.h>
#include <math.h>

#define Bsz   64
#define Lseq  1024
#define Din   512
#define Hdim  1024
// gate rows in W: r = g*Hdim + j, g in {0:i, 1:f, 2:c, 3:o}

// mask dtype flag: 0 = int32, 1 = uint8 (bool), 2 = float32
__global__ void rgn2_detect_mask(const unsigned int* __restrict__ mask, int* __restrict__ flag) {
    if (threadIdx.x == 0 && blockIdx.x == 0) {
        unsigned int w = mask[0];            // (b=0,t=0..): always "true" region
        int f;
        if (w == 1u)               f = 0;    // int32 ones
        else if (w == 0x01010101u) f = 1;    // packed bool bytes
        else if (w == 0x3F800000u) f = 2;    // float32 1.0f
        else                       f = 1;    // fallback: treat as bytes
        *flag = f;
    }
}

// One timestep. Grid: 256 blocks x 256 threads (4 waves/block, 1 block/CU).
// Block covers 4 h-units (j) x all 64 batches. Wave: lanes = 32 b x 2 j.
__launch_bounds__(256, 1)
__global__ void rgn2_lstm_step(const float* __restrict__ x,     // (B,L,D)
                               const void*  __restrict__ maskp, // (B,L) dtype per flag
                               const float* __restrict__ w_ih,  // (4H,D)
                               const float* __restrict__ w_hh,  // (4H,H)
                               const float* __restrict__ b_ih,  // (4H)
                               const float* __restrict__ b_hh,  // (4H)
                               const float* __restrict__ wci,   // (H)
                               const float* __restrict__ wcf,   // (H)
                               const float* __restrict__ wco,   // (H)
                               float* __restrict__ out,         // outs | hx | cx
                               const int* __restrict__ flagp,
                               int t)
{
    constexpr int C   = 128;   // k-chunk
    constexpr int PAD = 129;   // LDS row stride in floats (conflict-free columns)
    __shared__ float lds_xh[Bsz * PAD];    // 33 KB

    const int tid  = threadIdx.x;
    const int wid  = tid >> 6;
    const int lane = tid & 63;
    const int jh   = lane >> 5;                       // which of the wave's 2 j
    const int b    = ((wid & 1) << 5) | (lane & 31);  // batch index
    const int j    = (blockIdx.x << 2) + ((wid >> 1) << 1) + jh;

    float* cstate = out + (size_t)Bsz * Lseq * Hdim + (size_t)Bsz * Hdim; // cx region

    float acc0 = 0.f, acc1 = 0.f, acc2 = 0.f, acc3 = 0.f;  // i,f,c,o preacts

    const int nchunk = (t == 0) ? (Din / C) : ((Din + Hdim) / C);

    for (int ch = 0; ch < nchunk; ++ch) {
        const int k0 = ch * C;
        // ---- stage xh[64][128] into LDS (scalar: conflict-free writes) ----
        if (k0 < Din) {
            #pragma unroll
            for (int i = 0; i < 32; ++i) {
                int idx = tid + (i << 8);          // 0..8191
                int sb  = idx >> 7;                // 0..63
                int kk  = idx & 127;
                lds_xh[sb * PAD + kk] = x[((size_t)sb * Lseq + t) * Din + (k0 + kk)];
            }
        } else {
            const int kh0 = k0 - Din;
            #pragma unroll
            for (int i = 0; i < 32; ++i) {
                int idx = tid + (i << 8);
                int sb  = idx >> 7;
                int kk  = idx & 127;
                lds_xh[sb * PAD + kk] = out[((size_t)sb * Lseq + (t - 1)) * Hdim + (kh0 + kk)];
            }
        }
        __syncthreads();

        // ---- compute: 4 gate rows for this lane's (b, j) over this chunk ----
        const float* base = (k0 < Din) ? (w_ih + k0) : (w_hh + (k0 - Din));
        const size_t ldw  = (k0 < Din) ? (size_t)Din : (size_t)Hdim;
        const float* ws0  = base + (size_t)(0 * Hdim + j) * ldw;
        const float* ws1  = base + (size_t)(1 * Hdim + j) * ldw;
        const float* ws2  = base + (size_t)(2 * Hdim + j) * ldw;
        const float* ws3  = base + (size_t)(3 * Hdim + j) * ldw;
        const float* xrow = lds_xh + b * PAD;

        #pragma unroll 4
        for (int k4 = 0; k4 < C / 4; ++k4) {
            const int kb = k4 << 2;
            float4 w0 = *(const float4*)(ws0 + kb);
            float4 w1 = *(const float4*)(ws1 + kb);
            float4 w2 = *(const float4*)(ws2 + kb);
            float4 w3 = *(const float4*)(ws3 + kb);
            float x0 = xrow[kb + 0], x1 = xrow[kb + 1];
            float x2 = xrow[kb + 2], x3 = xrow[kb + 3];
            acc0 = fmaf(w0.x, x0, fmaf(w0.y, x1, fmaf(w0.z, x2, fmaf(w0.w, x3, acc0))));
            acc1 = fmaf(w1.x, x0, fmaf(w1.y, x1, fmaf(w1.z, x2, fmaf(w1.w, x3, acc1))));
            acc2 = fmaf(w2.x, x0, fmaf(w2.y, x1, fmaf(w2.z, x2, fmaf(w2.w, x3, acc2))));
            acc3 = fmaf(w3.x, x0, fmaf(w3.y, x1, fmaf(w3.z, x2, fmaf(w3.w, x3, acc3))));
        }
        __syncthreads();
    }

    // ---- gates / state update ----
    const int r0 = j, r1 = Hdim + j, r2 = 2 * Hdim + j, r3 = 3 * Hdim + j;
    acc0 += b_ih[r0] + b_hh[r0];
    acc1 += b_ih[r1] + b_hh[r1];
    acc2 += b_ih[r2] + b_hh[r2];
    acc3 += b_ih[r3] + b_hh[r3];

    const int fl = *flagp;
    const size_t mi = (size_t)b * Lseq + t;
    bool m;
    if (fl == 0)      m = ((const int*)maskp)[mi] != 0;
    else if (fl == 1) m = ((const unsigned char*)maskp)[mi] != 0;
    else              m = ((const float*)maskp)[mi] != 0.0f;

    const float c_old = (t == 0) ? 0.f : cstate[(size_t)b * Hdim + j];

    const float ig = 1.f / (1.f + expf(-(acc0 + wci[j] * c_old)));
    const float fg = 1.f / (1.f + expf(-(acc1 + wcf[j] * c_old)));
    const float gg = tanhf(acc2);
    const float cy = fg * c_old + ig * gg;
    const float og = 1.f / (1.f + expf(-(acc3 + wco[j] * cy)));
    const float hy = og * tanhf(cy);

    float hout;
    if (m) {
        cstate[(size_t)b * Hdim + j] = cy;
        hout = hy;
    } else {
        hout = (t == 0) ? 0.f : out[((size_t)b * Lseq + (t - 1)) * Hdim + j];
    }
    out[((size_t)b * Lseq + t) * Hdim + j] = hout;
}

// hx = outs[:, L-1, :]
__global__ void rgn2_copy_hx(float* __restrict__ out) {
    size_t i = (size_t)blockIdx.x * blockDim.x + threadIdx.x;  // < B*H
    size_t b = i >> 10;
    size_t j = i & 1023;
    out[(size_t)Bsz * Lseq * Hdim + i] = out[(b * Lseq + (Lseq - 1)) * Hdim + j];
}

extern "C" void kernel_launch(void* const* d_in, const int* in_sizes, int n_in,
                              void* d_out, int out_size, void* d_ws, size_t ws_size,
                              hipStream_t stream) {
    const float* x    = (const float*)d_in[0];
    const void*  mask = d_in[1];
    const float* w_ih = (const float*)d_in[2];
    const float* w_hh = (const float*)d_in[3];
    const float* b_ih = (const float*)d_in[4];
    const float* b_hh = (const float*)d_in[5];
    const float* wci  = (const float*)d_in[6];
    const float* wcf  = (const float*)d_in[7];
    const float* wco  = (const float*)d_in[8];
    float* out = (float*)d_out;
    int* flag  = (int*)d_ws;

    rgn2_detect_mask<<<1, 64, 0, stream>>>((const unsigned int*)mask, flag);
    for (int t = 0; t < Lseq; ++t) {
        rgn2_lstm_step<<<256, 256, 0, stream>>>(x, mask, w_ih, w_hh, b_ih, b_hh,
                                                wci, wcf, wco, out, flag, t);
    }
    rgn2_copy_hx<<<256, 256, 0, stream>>>(out);
}

// Round 3
// 32658.505 us; speedup vs baseline: 2.3938x; 2.3938x over previous
//
#include <hip/hip_runtime.h>
#include <math.h>
#include <stdint.h>

#define Bsz   64
#define Lseq  1024
#define Din   512
#define Hdim  1024

__device__ __forceinline__ uint32_t bf16rne(float v) {
    uint32_t u = __float_as_uint(v);
    return (u + 0x7FFFu + ((u >> 16) & 1u)) >> 16;
}

// mask dtype flag: 0 = int32, 1 = uint8 (bool), 2 = float32
__global__ void rgn2_detect_mask(const unsigned int* __restrict__ mask, int* __restrict__ flag) {
    if (threadIdx.x == 0 && blockIdx.x == 0) {
        unsigned int w = mask[0];
        int f;
        if (w == 1u)               f = 0;
        else if (w == 0x01010101u) f = 1;
        else if (w == 0x3F800000u) f = 2;
        else                       f = 1;
        *flag = f;
    }
}

// x (B,L,D) fp32 -> bf16, 8 elems/thread. Grid exact: B*L*D/8 / 256 blocks.
__global__ void rgn2_cvt_x(const float* __restrict__ x, uint4* __restrict__ xbf) {
    size_t i = (size_t)blockIdx.x * blockDim.x + threadIdx.x;
    const float4* s = (const float4*)x + i * 2;
    float4 a = s[0], b = s[1];
    uint4 u;
    u.x = bf16rne(a.x) | (bf16rne(a.y) << 16);
    u.y = bf16rne(a.z) | (bf16rne(a.w) << 16);
    u.z = bf16rne(b.x) | (bf16rne(b.y) << 16);
    u.w = bf16rne(b.z) | (bf16rne(b.w) << 16);
    xbf[i] = u;
}

// One timestep. Grid 256 x 512 (8 waves = 2/SIMD). Wave = 64 lanes = 64 batches,
// wave-uniform (j, gate-pair) -> scalar (SGPR) W loads. Activations stream as
// bf16 through double-buffered swizzled LDS.
// MODE: 2 = x-bf16 + h-bf16, 1 = x-f32 + h-bf16, 0 = all-f32.
template<int MODE>
__launch_bounds__(512, 2)
__global__ void rgn2_lstm_step(const float* __restrict__ x,        // (B,L,D) f32
                               const uint16_t* __restrict__ xbf,   // (B,L,D) bf16
                               const uint16_t* __restrict__ hbf_r, // (B,H) bf16  h_{t-1}
                               uint16_t* __restrict__ hbf_w,       // (B,H) bf16  h_t
                               const void*  __restrict__ maskp,
                               const float* __restrict__ w_ih,     // (4H,D)
                               const float* __restrict__ w_hh,     // (4H,H)
                               const float* __restrict__ b_ih,
                               const float* __restrict__ b_hh,
                               const float* __restrict__ wci,
                               const float* __restrict__ wcf,
                               const float* __restrict__ wco,
                               float* __restrict__ out,            // outs | hx | cx
                               const int* __restrict__ flagp,
                               int t)
{
    // chunk = 256 k x 64 b bf16 = 32 k8-cells x 64 b, 16B cells, XOR-swizzled
    __shared__ uint4 hbuf[2][32][64];   // 64 KB (excg aliases this after last use)

    const int tid  = threadIdx.x;
    const int lane = tid & 63;                                   // batch b in compute
    const int wid  = __builtin_amdgcn_readfirstlane(tid >> 6);
    const int jj   = wid >> 1;                                   // 0..3
    const int gh   = wid & 1;                                    // gate pair
    const int j    = (blockIdx.x << 2) + jj;
    const int g0   = gh << 1, g1 = (gh << 1) + 1;

    float* cstate = out + (size_t)Bsz * Lseq * Hdim + (size_t)Bsz * Hdim;

    const int sk8 = tid & 31;    // staging cell k8
    const int sb0 = tid >> 5;    // staging batch base

    const int nc = (t == 0) ? 2 : 6;

    float a0e = 0.f, a0o = 0.f, a1e = 0.f, a1o = 0.f;

    uint4  ureg[4];
    float4 sreg[4][2];

    auto issue_loads = [&](int kc) {
        #pragma unroll
        for (int i = 0; i < 4; ++i) {
            const int b = sb0 + (i << 4);
            if (kc < Din) {
                if constexpr (MODE == 2) {
                    ureg[i] = *(const uint4*)(xbf + ((size_t)b * Lseq + t) * Din + kc + sk8 * 8);
                } else {
                    const float* src = x + ((size_t)b * Lseq + t) * Din + kc + sk8 * 8;
                    sreg[i][0] = *(const float4*)(src);
                    sreg[i][1] = *(const float4*)(src + 4);
                }
            } else {
                if constexpr (MODE >= 1) {
                    ureg[i] = *(const uint4*)(hbf_r + (size_t)b * Hdim + (kc - Din) + sk8 * 8);
                } else {
                    const float* src = out + ((size_t)b * Lseq + (t - 1)) * Hdim + (kc - Din) + sk8 * 8;
                    sreg[i][0] = *(const float4*)(src);
                    sreg[i][1] = *(const float4*)(src + 4);
                }
            }
        }
    };
    auto write_lds = [&](int buf, int kc) {
        const bool direct = (MODE == 2) || (MODE >= 1 && kc >= Din);
        #pragma unroll
        for (int i = 0; i < 4; ++i) {
            const int b = sb0 + (i << 4);
            uint4 u;
            if (direct) {
                u = ureg[i];
            } else {
                u.x = bf16rne(sreg[i][0].x) | (bf16rne(sreg[i][0].y) << 16);
                u.y = bf16rne(sreg[i][0].z) | (bf16rne(sreg[i][0].w) << 16);
                u.z = bf16rne(sreg[i][1].x) | (bf16rne(sreg[i][1].y) << 16);
                u.w = bf16rne(sreg[i][1].z) | (bf16rne(sreg[i][1].w) << 16);
            }
            hbuf[buf][sk8][b ^ (sk8 & 7)] = u;
        }
    };

    // prologue: stage chunk 0
    issue_loads(0);
    write_lds(0, 0);
    __syncthreads();

    for (int c = 0; c < nc; ++c) {
        const bool more = (c + 1 < nc);
        const int  kc1  = (c + 1) << 8;
        if (more) issue_loads(kc1);

        // compute chunk c
        {
            const float* wr0;
            const float* wr1;
            if (c < 2) {
                wr0 = w_ih + (size_t)(g0 * Hdim + j) * Din + (c << 8);
                wr1 = w_ih + (size_t)(g1 * Hdim + j) * Din + (c << 8);
            } else {
                wr0 = w_hh + (size_t)(g0 * Hdim + j) * Hdim + ((c - 2) << 8);
                wr1 = w_hh + (size_t)(g1 * Hdim + j) * Hdim + ((c - 2) << 8);
            }
            const uint4* hb = &hbuf[c & 1][0][0];
            #pragma unroll 4
            for (int k8 = 0; k8 < 32; ++k8) {
                uint4 hv = hb[(k8 << 6) + (lane ^ (k8 & 7))];
                float h0 = __uint_as_float(hv.x << 16);
                float h1 = __uint_as_float(hv.x & 0xFFFF0000u);
                float h2 = __uint_as_float(hv.y << 16);
                float h3 = __uint_as_float(hv.y & 0xFFFF0000u);
                float h4 = __uint_as_float(hv.z << 16);
                float h5 = __uint_as_float(hv.z & 0xFFFF0000u);
                float h6 = __uint_as_float(hv.w << 16);
                float h7 = __uint_as_float(hv.w & 0xFFFF0000u);
                const float* wa = wr0 + (k8 << 3);
                const float* wb = wr1 + (k8 << 3);
                a0e = fmaf(wa[0], h0, a0e);
                a0o = fmaf(wa[1], h1, a0o);
                a0e = fmaf(wa[2], h2, a0e);
                a0o = fmaf(wa[3], h3, a0o);
                a0e = fmaf(wa[4], h4, a0e);
                a0o = fmaf(wa[5], h5, a0o);
                a0e = fmaf(wa[6], h6, a0e);
                a0o = fmaf(wa[7], h7, a0o);
                a1e = fmaf(wb[0], h0, a1e);
                a1o = fmaf(wb[1], h1, a1o);
                a1e = fmaf(wb[2], h2, a1e);
                a1o = fmaf(wb[3], h3, a1o);
                a1e = fmaf(wb[4], h4, a1e);
                a1o = fmaf(wb[5], h5, a1o);
                a1e = fmaf(wb[6], h6, a1e);
                a1o = fmaf(wb[7], h7, a1o);
            }
        }

        if (more) write_lds((c + 1) & 1, kc1);
        __syncthreads();
    }

    // gate exchange (aliases hbuf; all hbuf reads completed before last barrier)
    float* excg = reinterpret_cast<float*>(hbuf);   // [16][64]
    excg[(((g0 << 2) + jj) << 6) + lane] = a0e + a0o;
    excg[(((g1 << 2) + jj) << 6) + lane] = a1e + a1o;
    __syncthreads();

    if (tid < 256) {
        const int b   = tid & 63;
        const int jj2 = __builtin_amdgcn_readfirstlane(tid >> 6);
        const int j2  = (blockIdx.x << 2) + jj2;

        float pi = excg[((0 * 4 + jj2) << 6) + b] + b_ih[j2]            + b_hh[j2];
        float pf = excg[((1 * 4 + jj2) << 6) + b] + b_ih[Hdim + j2]     + b_hh[Hdim + j2];
        float pc = excg[((2 * 4 + jj2) << 6) + b] + b_ih[2 * Hdim + j2] + b_hh[2 * Hdim + j2];
        float po = excg[((3 * 4 + jj2) << 6) + b] + b_ih[3 * Hdim + j2] + b_hh[3 * Hdim + j2];

        const int fl = *flagp;
        const size_t mi = (size_t)b * Lseq + t;
        bool m;
        if (fl == 0)      m = ((const int*)maskp)[mi] != 0;
        else if (fl == 1) m = ((const unsigned char*)maskp)[mi] != 0;
        else              m = ((const float*)maskp)[mi] != 0.0f;

        const float c_old = (t == 0) ? 0.f : cstate[(size_t)b * Hdim + j2];

        const float ig = 1.f / (1.f + expf(-(pi + wci[j2] * c_old)));
        const float fg = 1.f / (1.f + expf(-(pf + wcf[j2] * c_old)));
        const float gg = tanhf(pc);
        const float cy = fg * c_old + ig * gg;
        const float og = 1.f / (1.f + expf(-(po + wco[j2] * cy)));
        const float hy = og * tanhf(cy);

        float hout;
        if (m) {
            cstate[(size_t)b * Hdim + j2] = cy;
            hout = hy;
        } else {
            hout = (t == 0) ? 0.f : out[((size_t)b * Lseq + (t - 1)) * Hdim + j2];
        }
        out[((size_t)b * Lseq + t) * Hdim + j2] = hout;
        if constexpr (MODE >= 1) {
            hbf_w[(size_t)b * Hdim + j2] = (uint16_t)bf16rne(hout);
        }
    }
}

// hx = outs[:, L-1, :]
__global__ void rgn2_copy_hx(float* __restrict__ out) {
    size_t i = (size_t)blockIdx.x * blockDim.x + threadIdx.x;  // < B*H
    size_t b = i >> 10;
    size_t j = i & 1023;
    out[(size_t)Bsz * Lseq * Hdim + i] = out[(b * Lseq + (Lseq - 1)) * Hdim + j];
}

extern "C" void kernel_launch(void* const* d_in, const int* in_sizes, int n_in,
                              void* d_out, int out_size, void* d_ws, size_t ws_size,
                              hipStream_t stream) {
    const float* x    = (const float*)d_in[0];
    const void*  mask = d_in[1];
    const float* w_ih = (const float*)d_in[2];
    const float* w_hh = (const float*)d_in[3];
    const float* b_ih = (const float*)d_in[4];
    const float* b_hh = (const float*)d_in[5];
    const float* wci  = (const float*)d_in[6];
    const float* wcf  = (const float*)d_in[7];
    const float* wco  = (const float*)d_in[8];
    float* out = (float*)d_out;

    int*      flag = (int*)d_ws;
    uint16_t* hbf  = (uint16_t*)((char*)d_ws + 1024);                       // 2 x B*H bf16
    uint16_t* xbf  = (uint16_t*)((char*)d_ws + 1024 + 2ull * Bsz * Hdim * 2);

    const size_t need_h = 1024 + 2ull * Bsz * Hdim * 2;                      // ~263 KB
    const size_t need_x = need_h + 2ull * Bsz * Lseq * Din;                  // + 64 MB

    rgn2_detect_mask<<<1, 64, 0, stream>>>((const unsigned int*)mask, flag);

    uint16_t* h0 = hbf;
    uint16_t* h1 = hbf + (size_t)Bsz * Hdim;

    if (ws_size >= need_x) {
        rgn2_cvt_x<<<(Bsz * Lseq * Din / 8) / 256, 256, 0, stream>>>(x, (uint4*)xbf);
        for (int t = 0; t < Lseq; ++t) {
            rgn2_lstm_step<2><<<256, 512, 0, stream>>>(x, xbf, (t & 1) ? h0 : h1, (t & 1) ? h1 : h0,
                                                       mask, w_ih, w_hh, b_ih, b_hh,
                                                       wci, wcf, wco, out, flag, t);
        }
    } else if (ws_size >= need_h) {
        for (int t = 0; t < Lseq; ++t) {
            rgn2_lstm_step<1><<<256, 512, 0, stream>>>(x, xbf, (t & 1) ? h0 : h1, (t & 1) ? h1 : h0,
                                                       mask, w_ih, w_hh, b_ih, b_hh,
                                                       wci, wcf, wco, out, flag, t);
        }
    } else {
        for (int t = 0; t < Lseq; ++t) {
            rgn2_lstm_step<0><<<256, 512, 0, stream>>>(x, xbf, h0, h0,
                                                       mask, w_ih, w_hh, b_ih, b_hh,
                                                       wci, wcf, wco, out, flag, t);
        }
    }
    rgn2_copy_hx<<<256, 256, 0, stream>>>(out);
}

// Round 4
// 13743.262 us; speedup vs baseline: 5.6885x; 2.3763x over previous
//
#include <hip/hip_runtime.h>
#include <math.h>
#include <stdint.h>

#define Bsz   64
#define Lseq  1024
#define Din   512
#define Hdim  1024
#define Kcat  1536
#define R4H   4096

typedef __attribute__((ext_vector_type(8))) short short8;
typedef __attribute__((ext_vector_type(4))) float f32x4;

__device__ __forceinline__ uint32_t bf16rne(float v) {
    uint32_t u = __float_as_uint(v);
    return (u + 0x7FFFu + ((u >> 16) & 1u)) >> 16;
}

// mask dtype flag: 0 = int32, 1 = uint8 (bool), 2 = float32
__global__ void rgn2_detect_mask(const unsigned int* __restrict__ mask, int* __restrict__ flag) {
    if (threadIdx.x == 0 && blockIdx.x == 0) {
        unsigned int w = mask[0];
        int f;
        if (w == 1u)               f = 0;
        else if (w == 0x01010101u) f = 1;
        else if (w == 0x3F800000u) f = 2;
        else                       f = 1;
        *flag = f;
    }
}

// x (B,L,D) fp32 -> bf16 flat. 8 elems/thread.
__global__ void rgn2_cvt_x(const float* __restrict__ x, uint4* __restrict__ xbf) {
    size_t i = (size_t)blockIdx.x * blockDim.x + threadIdx.x;
    const float4* s = (const float4*)x + i * 2;
    float4 a = s[0], b = s[1];
    uint4 u;
    u.x = bf16rne(a.x) | (bf16rne(a.y) << 16);
    u.y = bf16rne(a.z) | (bf16rne(a.w) << 16);
    u.z = bf16rne(b.x) | (bf16rne(b.y) << 16);
    u.w = bf16rne(b.z) | (bf16rne(b.w) << 16);
    xbf[i] = u;
}

// W split hi/lo bf16, rows permuted so each block's 16 rows (4 j x 4 gates) are
// contiguous: r = g*1024 + j  ->  p = (j>>2)*16 + g*4 + (j&3).
__global__ void rgn2_cvt_w(const float* __restrict__ w_ih, const float* __restrict__ w_hh,
                           uint16_t* __restrict__ whi, uint16_t* __restrict__ wlo) {
    size_t i = (size_t)blockIdx.x * blockDim.x + threadIdx.x;   // < 4096*192
    int r  = (int)(i / 192);
    int k  = ((int)(i % 192)) * 8;
    int g  = r >> 10, j = r & 1023;
    int p  = ((j >> 2) << 4) + (g << 2) + (j & 3);
    const float* src = (k < Din) ? (w_ih + (size_t)r * Din + k)
                                 : (w_hh + (size_t)r * Hdim + (k - Din));
    float4 a = *(const float4*)src;
    float4 b = *(const float4*)(src + 4);
    float f[8] = {a.x, a.y, a.z, a.w, b.x, b.y, b.z, b.w};
    uint16_t hi[8], lo[8];
    #pragma unroll
    for (int e = 0; e < 8; ++e) {
        uint32_t h = bf16rne(f[e]);
        hi[e] = (uint16_t)h;
        lo[e] = (uint16_t)bf16rne(f[e] - __uint_as_float(h << 16));
    }
    *(uint4*)(whi + (size_t)p * Kcat + k) = *(uint4*)hi;
    *(uint4*)(wlo + (size_t)p * Kcat + k) = *(uint4*)lo;
}

// bsum[p(r)] = b_ih[r] + b_hh[r]
__global__ void rgn2_bias(const float* __restrict__ bih, const float* __restrict__ bhh,
                          float* __restrict__ bsum) {
    int r = blockIdx.x * 256 + threadIdx.x;
    int g = r >> 10, j = r & 1023;
    int p = ((j >> 2) << 4) + (g << 2) + (j & 3);
    bsum[p] = bih[r] + bhh[r];
}

// One timestep, MFMA path. 256 blocks x 512 thr (8 waves). Block: 4 j-units
// (16 gate-rows). Wave w: k-slices [6w, 6w+6) of K=1536; fp32 partial
// accumulators reduced via LDS. No LDS in main loop: W-frag (A-op) and
// act-frag (B-op) are direct 16B/lane global loads (L1-line reuse across ks).
// MODE 2: x pre-converted bf16 (xbf); MODE 1: x f32 converted in-register.
template<int MODE>
__launch_bounds__(512, 2)
__global__ void rgn2_step_mfma(const float* __restrict__ x,
                               const uint16_t* __restrict__ xbf,
                               const uint16_t* __restrict__ hbf_r,
                               uint16_t* __restrict__ hbf_w,
                               const uint16_t* __restrict__ whi,
                               const uint16_t* __restrict__ wlo,
                               const float* __restrict__ bsum,
                               const float* __restrict__ wci,
                               const float* __restrict__ wcf,
                               const float* __restrict__ wco,
                               const void*  __restrict__ maskp,
                               float* __restrict__ out,          // outs | hx | cx
                               const int* __restrict__ flagp,
                               int t)
{
    __shared__ float part[8][16][64];   // 32 KB k-split partials

    const int tid  = threadIdx.x;
    const int lane = tid & 63;
    const int w    = __builtin_amdgcn_readfirstlane(tid >> 6);  // 0..7
    const int l15  = lane & 15;
    const int l4   = lane >> 4;                                  // 0..3

    f32x4 acc[4] = {{0.f,0.f,0.f,0.f},{0.f,0.f,0.f,0.f},
                    {0.f,0.f,0.f,0.f},{0.f,0.f,0.f,0.f}};

    // A-operand (W) per-lane base: row = lane&15 within block's 16 permuted rows
    const int prow = (blockIdx.x << 4) + l15;
    const uint16_t* whB = whi + (size_t)prow * Kcat + (l4 << 3);
    const uint16_t* wlB = wlo + (size_t)prow * Kcat + (l4 << 3);

    // B-operand (activations) per-lane bases: col(b) = bt*16 + (lane&15)
    const float*    xfB[4];
    const uint16_t* xbB[4];
    const uint16_t* hbB[4];
    #pragma unroll
    for (int bt = 0; bt < 4; ++bt) {
        const int b = (bt << 4) + l15;
        if constexpr (MODE == 2) xbB[bt] = xbf + ((size_t)b * Lseq + t) * Din + (l4 << 3);
        else                     xfB[bt] = x   + ((size_t)b * Lseq + t) * Din + (l4 << 3);
        hbB[bt] = hbf_r + (size_t)b * Hdim + (l4 << 3);
    }

    const int ks0    = w * 6;
    const int ks_end = (t == 0) ? 16 : 48;     // t=0: h==0, x-slices only

    auto do_ks = [&](int ks) {
        const int kc = ks << 5;
        short8 ah = *(const short8*)(whB + kc);
        short8 al = *(const short8*)(wlB + kc);
        short8 bf[4];
        if (kc < Din) {
            #pragma unroll
            for (int bt = 0; bt < 4; ++bt) {
                if constexpr (MODE == 2) {
                    bf[bt] = *(const short8*)(xbB[bt] + kc);
                } else {
                    const float* p = xfB[bt] + kc;
                    float4 a = *(const float4*)p;
                    float4 c = *(const float4*)(p + 4);
                    short8 r;
                    r[0] = (short)bf16rne(a.x); r[1] = (short)bf16rne(a.y);
                    r[2] = (short)bf16rne(a.z); r[3] = (short)bf16rne(a.w);
                    r[4] = (short)bf16rne(c.x); r[5] = (short)bf16rne(c.y);
                    r[6] = (short)bf16rne(c.z); r[7] = (short)bf16rne(c.w);
                    bf[bt] = r;
                }
            }
        } else {
            #pragma unroll
            for (int bt = 0; bt < 4; ++bt)
                bf[bt] = *(const short8*)(hbB[bt] + (kc - Din));
        }
        #pragma unroll
        for (int bt = 0; bt < 4; ++bt)
            acc[bt] = __builtin_amdgcn_mfma_f32_16x16x32_bf16(ah, bf[bt], acc[bt], 0, 0, 0);
        #pragma unroll
        for (int bt = 0; bt < 4; ++bt)
            acc[bt] = __builtin_amdgcn_mfma_f32_16x16x32_bf16(al, bf[bt], acc[bt], 0, 0, 0);
    };

    if (ks0 + 6 <= ks_end) {
        #pragma unroll
        for (int u = 0; u < 6; ++u) do_ks(ks0 + u);
    } else {
        const int nu = ks_end - ks0;
        for (int u = 0; u < nu; ++u) do_ks(ks0 + u);
    }

    // stash partials: D layout col=lane&15 (b), row=(lane>>4)*4+reg (ridx)
    #pragma unroll
    for (int bt = 0; bt < 4; ++bt)
        #pragma unroll
        for (int rg = 0; rg < 4; ++rg)
            part[w][(l4 << 2) + rg][(bt << 4) + l15] = acc[bt][rg];

    // epilogue pre-loads (issued before the barrier to hide latency)
    const bool epi = tid < 256;
    int b = 0, jj = 0, j = 0;
    float c_old = 0.f, wciv = 0.f, wcfv = 0.f, wcov = 0.f, hprev = 0.f;
    float bsv[4] = {0.f, 0.f, 0.f, 0.f};
    bool m = false;
    float* cstate = out + (size_t)Bsz * Lseq * Hdim + (size_t)Bsz * Hdim;
    if (epi) {
        jj = tid & 3; b = tid >> 2; j = (blockIdx.x << 2) + jj;
        const int fl = *flagp;
        const size_t mi = (size_t)b * Lseq + t;
        if (fl == 0)      m = ((const int*)maskp)[mi] != 0;
        else if (fl == 1) m = ((const unsigned char*)maskp)[mi] != 0;
        else              m = ((const float*)maskp)[mi] != 0.0f;
        c_old = (t == 0) ? 0.f : cstate[(size_t)b * Hdim + j];
        wciv = wci[j]; wcfv = wcf[j]; wcov = wco[j];
        #pragma unroll
        for (int g = 0; g < 4; ++g) bsv[g] = bsum[(blockIdx.x << 4) + (g << 2) + jj];
        if (t > 0) hprev = out[((size_t)b * Lseq + (t - 1)) * Hdim + j];
    }
    __syncthreads();
    if (epi) {
        float pre[4];
        #pragma unroll
        for (int g = 0; g < 4; ++g) {
            float s = 0.f;
            #pragma unroll
            for (int w8 = 0; w8 < 8; ++w8) s += part[w8][(g << 2) + jj][b];
            pre[g] = s + bsv[g];
        }
        const float ig = 1.f / (1.f + expf(-(pre[0] + wciv * c_old)));
        const float fg = 1.f / (1.f + expf(-(pre[1] + wcfv * c_old)));
        const float gg = tanhf(pre[2]);
        const float cy = fg * c_old + ig * gg;
        const float og = 1.f / (1.f + expf(-(pre[3] + wcov * cy)));
        const float hy = og * tanhf(cy);
        float hout;
        if (m) { cstate[(size_t)b * Hdim + j] = cy; hout = hy; }
        else   { hout = (t == 0) ? 0.f : hprev; }
        out[((size_t)b * Lseq + t) * Hdim + j] = hout;
        hbf_w[(size_t)b * Hdim + j] = (uint16_t)bf16rne(hout);
    }
}

// Fallback (round-1, known-correct, flag-only ws): one step, all-fp32 VALU.
__launch_bounds__(256, 1)
__global__ void rgn2_step_v1(const float* __restrict__ x, const void* __restrict__ maskp,
                             const float* __restrict__ w_ih, const float* __restrict__ w_hh,
                             const float* __restrict__ b_ih, const float* __restrict__ b_hh,
                             const float* __restrict__ wci, const float* __restrict__ wcf,
                             const float* __restrict__ wco, float* __restrict__ out,
                             const int* __restrict__ flagp, int t)
{
    constexpr int C = 128, PAD = 129;
    __shared__ float lds_xh[Bsz * PAD];
    const int tid = threadIdx.x, wid = tid >> 6, lane = tid & 63;
    const int jh = lane >> 5;
    const int b = ((wid & 1) << 5) | (lane & 31);
    const int j = (blockIdx.x << 2) + ((wid >> 1) << 1) + jh;
    float* cstate = out + (size_t)Bsz * Lseq * Hdim + (size_t)Bsz * Hdim;
    float acc0 = 0.f, acc1 = 0.f, acc2 = 0.f, acc3 = 0.f;
    const int nchunk = (t == 0) ? (Din / C) : ((Din + Hdim) / C);
    for (int ch = 0; ch < nchunk; ++ch) {
        const int k0 = ch * C;
        if (k0 < Din) {
            #pragma unroll
            for (int i = 0; i < 32; ++i) {
                int idx = tid + (i << 8), sb = idx >> 7, kk = idx & 127;
                lds_xh[sb * PAD + kk] = x[((size_t)sb * Lseq + t) * Din + (k0 + kk)];
            }
        } else {
            const int kh0 = k0 - Din;
            #pragma unroll
            for (int i = 0; i < 32; ++i) {
                int idx = tid + (i << 8), sb = idx >> 7, kk = idx & 127;
                lds_xh[sb * PAD + kk] = out[((size_t)sb * Lseq + (t - 1)) * Hdim + (kh0 + kk)];
            }
        }
        __syncthreads();
        const float* base = (k0 < Din) ? (w_ih + k0) : (w_hh + (k0 - Din));
        const size_t ldw = (k0 < Din) ? (size_t)Din : (size_t)Hdim;
        const float* ws0 = base + (size_t)(0 * Hdim + j) * ldw;
        const float* ws1 = base + (size_t)(1 * Hdim + j) * ldw;
        const float* ws2 = base + (size_t)(2 * Hdim + j) * ldw;
        const float* ws3 = base + (size_t)(3 * Hdim + j) * ldw;
        const float* xrow = lds_xh + b * PAD;
        #pragma unroll 4
        for (int k4 = 0; k4 < C / 4; ++k4) {
            const int kb = k4 << 2;
            float4 w0 = *(const float4*)(ws0 + kb);
            float4 w1 = *(const float4*)(ws1 + kb);
            float4 w2 = *(const float4*)(ws2 + kb);
            float4 w3 = *(const float4*)(ws3 + kb);
            float x0 = xrow[kb], x1 = xrow[kb + 1], x2 = xrow[kb + 2], x3 = xrow[kb + 3];
            acc0 = fmaf(w0.x, x0, fmaf(w0.y, x1, fmaf(w0.z, x2, fmaf(w0.w, x3, acc0))));
            acc1 = fmaf(w1.x, x0, fmaf(w1.y, x1, fmaf(w1.z, x2, fmaf(w1.w, x3, acc1))));
            acc2 = fmaf(w2.x, x0, fmaf(w2.y, x1, fmaf(w2.z, x2, fmaf(w2.w, x3, acc2))));
            acc3 = fmaf(w3.x, x0, fmaf(w3.y, x1, fmaf(w3.z, x2, fmaf(w3.w, x3, acc3))));
        }
        __syncthreads();
    }
    const int r0 = j, r1 = Hdim + j, r2 = 2 * Hdim + j, r3 = 3 * Hdim + j;
    acc0 += b_ih[r0] + b_hh[r0]; acc1 += b_ih[r1] + b_hh[r1];
    acc2 += b_ih[r2] + b_hh[r2]; acc3 += b_ih[r3] + b_hh[r3];
    const int fl = *flagp;
    const size_t mi = (size_t)b * Lseq + t;
    bool m;
    if (fl == 0)      m = ((const int*)maskp)[mi] != 0;
    else if (fl == 1) m = ((const unsigned char*)maskp)[mi] != 0;
    else              m = ((const float*)maskp)[mi] != 0.0f;
    const float c_old = (t == 0) ? 0.f : cstate[(size_t)b * Hdim + j];
    const float ig = 1.f / (1.f + expf(-(acc0 + wci[j] * c_old)));
    const float fg = 1.f / (1.f + expf(-(acc1 + wcf[j] * c_old)));
    const float gg = tanhf(acc2);
    const float cy = fg * c_old + ig * gg;
    const float og = 1.f / (1.f + expf(-(acc3 + wco[j] * cy)));
    const float hy = og * tanhf(cy);
    float hout;
    if (m) { cstate[(size_t)b * Hdim + j] = cy; hout = hy; }
    else   { hout = (t == 0) ? 0.f : out[((size_t)b * Lseq + (t - 1)) * Hdim + j]; }
    out[((size_t)b * Lseq + t) * Hdim + j] = hout;
}

// hx = outs[:, L-1, :]
__global__ void rgn2_copy_hx(float* __restrict__ out) {
    size_t i = (size_t)blockIdx.x * blockDim.x + threadIdx.x;
    size_t b = i >> 10, j = i & 1023;
    out[(size_t)Bsz * Lseq * Hdim + i] = out[(b * Lseq + (Lseq - 1)) * Hdim + j];
}

extern "C" void kernel_launch(void* const* d_in, const int* in_sizes, int n_in,
                              void* d_out, int out_size, void* d_ws, size_t ws_size,
                              hipStream_t stream) {
    const float* x    = (const float*)d_in[0];
    const void*  mask = d_in[1];
    const float* w_ih = (const float*)d_in[2];
    const float* w_hh = (const float*)d_in[3];
    const float* b_ih = (const float*)d_in[4];
    const float* b_hh = (const float*)d_in[5];
    const float* wci  = (const float*)d_in[6];
    const float* wcf  = (const float*)d_in[7];
    const float* wco  = (const float*)d_in[8];
    float* out = (float*)d_out;

    // ws layout
    int*      flag = (int*)d_ws;
    float*    bsum = (float*)((char*)d_ws + 1024);
    uint16_t* hbf  = (uint16_t*)((char*)d_ws + 1024 + 16384);                  // 2 x B*H
    uint16_t* whi  = (uint16_t*)((char*)d_ws + 1024 + 16384 + 262144);
    uint16_t* wlo  = whi + (size_t)R4H * Kcat;
    uint16_t* xbf  = wlo + (size_t)R4H * Kcat;
    const size_t need1 = 1024 + 16384 + 262144 + 2ull * R4H * Kcat * 2;        // ~25.4 MB
    const size_t need2 = need1 + 2ull * Bsz * Lseq * Din;                      // ~92.5 MB

    rgn2_detect_mask<<<1, 64, 0, stream>>>((const unsigned int*)mask, flag);

    uint16_t* h0 = hbf;
    uint16_t* h1 = hbf + (size_t)Bsz * Hdim;

    if (ws_size >= need1) {
        rgn2_cvt_w<<<3072, 256, 0, stream>>>(w_ih, w_hh, whi, wlo);
        rgn2_bias<<<16, 256, 0, stream>>>(b_ih, b_hh, bsum);
        if (ws_size >= need2) {
            rgn2_cvt_x<<<16384, 256, 0, stream>>>(x, (uint4*)xbf);
            for (int t = 0; t < Lseq; ++t)
                rgn2_step_mfma<2><<<256, 512, 0, stream>>>(
                    x, xbf, (t & 1) ? h0 : h1, (t & 1) ? h1 : h0, whi, wlo, bsum,
                    wci, wcf, wco, mask, out, flag, t);
        } else {
            for (int t = 0; t < Lseq; ++t)
                rgn2_step_mfma<1><<<256, 512, 0, stream>>>(
                    x, xbf, (t & 1) ? h0 : h1, (t & 1) ? h1 : h0, whi, wlo, bsum,
                    wci, wcf, wco, mask, out, flag, t);
        }
    } else {
        for (int t = 0; t < Lseq; ++t)
            rgn2_step_v1<<<256, 256, 0, stream>>>(x, mask, w_ih, w_hh, b_ih, b_hh,
                                                  wci, wcf, wco, out, flag, t);
    }
    rgn2_copy_hx<<<256, 256, 0, stream>>>(out);
}